// Round 1
// baseline (466.451 us; speedup 1.0000x reference)
//
#include <hip/hip_runtime.h>

#define BATCH 32
#define NR 1024
#define NC 1024
#define EPS 0.001f
#define ITERS 10
#define ROWCHUNKS 8   // colsum row-splitting for parallelism

// ws layout (floats): r[BATCH*NR] | c[BATCH*NC] | part[BATCH*ROWCHUNKS*NC]
// total = 32768 + 32768 + 262144 floats = 1.25 MB

__global__ void init_c_kernel(float* __restrict__ c) {
    int idx = blockIdx.x * blockDim.x + threadIdx.x;
    if (idx < BATCH * NC) c[idx] = 1.0f;
}

// r[b,i] = 1 / sum_j (x[b,i,j] + EPS) * c[b,j]
// one wave (64 lanes) per row; 4 waves per block
__global__ void rowsum_kernel(const float* __restrict__ x,
                              const float* __restrict__ c,
                              float* __restrict__ r) {
    int wave = threadIdx.x >> 6;
    int lane = threadIdx.x & 63;
    int row  = blockIdx.x * 4 + wave;          // global row in [0, BATCH*NR)
    int b    = row >> 10;
    const float* xrow = x + (size_t)row * NC;
    const float* cb   = c + b * NC;
    float sum = 0.0f;
#pragma unroll
    for (int k = 0; k < 4; ++k) {
        int j = k * 256 + lane * 4;
        float4 xv = *(const float4*)(xrow + j);
        float4 cv = *(const float4*)(cb + j);
        sum += (xv.x + EPS) * cv.x + (xv.y + EPS) * cv.y +
               (xv.z + EPS) * cv.z + (xv.w + EPS) * cv.w;
    }
#pragma unroll
    for (int off = 32; off > 0; off >>= 1) sum += __shfl_xor(sum, off);
    if (lane == 0) r[row] = 1.0f / sum;
}

// part[b, ic, j] = sum_{i in chunk ic} r[b,i] * (x[b,i,j] + EPS)
// grid (jc, ic, b) = (4, ROWCHUNKS, BATCH), block 256: thread owns column j
__global__ void colsum_kernel(const float* __restrict__ x,
                              const float* __restrict__ r,
                              float* __restrict__ part) {
    int j  = blockIdx.x * 256 + threadIdx.x;
    int ic = blockIdx.y;
    int b  = blockIdx.z;
    const int rows_per_chunk = NR / ROWCHUNKS;   // 128
    const float* xp = x + ((size_t)b * NR + (size_t)ic * rows_per_chunk) * NC + j;
    const float* rp = r + b * NR + ic * rows_per_chunk;
    float sum = 0.0f;
#pragma unroll 8
    for (int i = 0; i < rows_per_chunk; ++i) {
        sum += rp[i] * (xp[(size_t)i * NC] + EPS);
    }
    part[((b * ROWCHUNKS + ic) * NC) + j] = sum;
}

// c[b,j] = 1 / sum_ic part[b,ic,j]
__global__ void colreduce_kernel(const float* __restrict__ part,
                                 float* __restrict__ c) {
    int idx = blockIdx.x * blockDim.x + threadIdx.x;   // b*NC + j
    int b = idx >> 10;
    int j = idx & (NC - 1);
    float sum = 0.0f;
#pragma unroll
    for (int ic = 0; ic < ROWCHUNKS; ++ic)
        sum += part[(b * ROWCHUNKS + ic) * NC + j];
    c[idx] = 1.0f / sum;
}

// out[b,i,j] = r[b,i] * (x[b,i,j] + EPS) * c[b,j], float4-vectorized
__global__ void final_kernel(const float* __restrict__ x,
                             const float* __restrict__ r,
                             const float* __restrict__ c,
                             float* __restrict__ out) {
    size_t idx = ((size_t)blockIdx.x * blockDim.x + threadIdx.x) * 4;
    int row = (int)(idx >> 10);          // b*NR + i
    int b   = row >> 10;
    int j   = (int)(idx & (NC - 1));
    float4 xv = *(const float4*)(x + idx);
    float4 cv = *(const float4*)(c + b * NC + j);
    float  rv = r[row];
    float4 o;
    o.x = rv * (xv.x + EPS) * cv.x;
    o.y = rv * (xv.y + EPS) * cv.y;
    o.z = rv * (xv.z + EPS) * cv.z;
    o.w = rv * (xv.w + EPS) * cv.w;
    *(float4*)(out + idx) = o;
}

extern "C" void kernel_launch(void* const* d_in, const int* in_sizes, int n_in,
                              void* d_out, int out_size, void* d_ws, size_t ws_size,
                              hipStream_t stream) {
    const float* x = (const float*)d_in[0];
    float* out = (float*)d_out;
    float* r    = (float*)d_ws;
    float* c    = r + BATCH * NR;
    float* part = c + BATCH * NC;

    init_c_kernel<<<(BATCH * NC) / 256, 256, 0, stream>>>(c);
    for (int t = 0; t < ITERS; ++t) {
        rowsum_kernel<<<(BATCH * NR) / 4, 256, 0, stream>>>(x, c, r);
        colsum_kernel<<<dim3(4, ROWCHUNKS, BATCH), 256, 0, stream>>>(x, r, part);
        colreduce_kernel<<<(BATCH * NC) / 256, 256, 0, stream>>>(part, c);
    }
    final_kernel<<<(BATCH * NR * NC / 4) / 256, 256, 0, stream>>>(x, r, c, out);
}

// Round 2
// 312.525 us; speedup vs baseline: 1.4925x; 1.4925x over previous
//
#include <hip/hip_runtime.h>
#include <hip/hip_fp16.h>

#define BATCH 32
#define N 1024
#define EPS 0.001f
#define ITERS 10
#define RCH 32            // row chunks for colsum partials
#define RPC (N / RCH)     // 32 rows per chunk

// ws layout (bytes):
//   xh   [BATCH*N*N] fp16   = 67,108,864 B
//   r    [BATCH*N]   fp32   = 131,072 B
//   c    [BATCH*N]   fp32   = 131,072 B
//   part [BATCH*RCH*N] fp32 = 4,194,304 B

// Fused: xh = fp16(x+eps); r = 1/rowsum(x+eps)   (first iteration, c0 = 1)
// one wave per row, 4 waves/block
__global__ void convert_rowsum_kernel(const float* __restrict__ x,
                                      __half* __restrict__ xh,
                                      float* __restrict__ r) {
    int wave = threadIdx.x >> 6, lane = threadIdx.x & 63;
    int row  = blockIdx.x * 4 + wave;          // [0, BATCH*N)
    const float* xrow = x + (size_t)row * N;
    __half*      hrow = xh + (size_t)row * N;
    float sum = 0.0f;
#pragma unroll
    for (int k = 0; k < 4; ++k) {
        int j = k * 256 + lane * 4;
        float4 xv = *(const float4*)(xrow + j);
        float a = xv.x + EPS, b = xv.y + EPS, cc = xv.z + EPS, d = xv.w + EPS;
        sum += a + b + cc + d;
        union { ushort4 u; __half2 h2[2]; } pk;
        pk.h2[0] = __floats2half2_rn(a, b);
        pk.h2[1] = __floats2half2_rn(cc, d);
        *(ushort4*)(hrow + j) = pk.u;
    }
#pragma unroll
    for (int off = 32; off; off >>= 1) sum += __shfl_xor(sum, off);
    if (!lane) r[row] = 1.0f / sum;
}

// r[row] = 1 / sum_j xh[row,j] * c[b,j]   (fp16 x, fp32 accumulate)
__global__ void rowsum_h_kernel(const __half* __restrict__ xh,
                                const float* __restrict__ c,
                                float* __restrict__ r) {
    int wave = threadIdx.x >> 6, lane = threadIdx.x & 63;
    int row  = blockIdx.x * 4 + wave;
    int b    = row >> 10;
    const __half* hrow = xh + (size_t)row * N;
    const float*  cb   = c + b * N;
    float sum = 0.0f;
#pragma unroll
    for (int k = 0; k < 2; ++k) {
        int j = k * 512 + lane * 8;
        float4 raw = *(const float4*)(hrow + j);       // 8 halves
        const __half* hp = (const __half*)&raw;
        float4 c0 = *(const float4*)(cb + j);
        float4 c1 = *(const float4*)(cb + j + 4);
        sum += c0.x * __half2float(hp[0]) + c0.y * __half2float(hp[1])
             + c0.z * __half2float(hp[2]) + c0.w * __half2float(hp[3])
             + c1.x * __half2float(hp[4]) + c1.y * __half2float(hp[5])
             + c1.z * __half2float(hp[6]) + c1.w * __half2float(hp[7]);
    }
#pragma unroll
    for (int off = 32; off; off >>= 1) sum += __shfl_xor(sum, off);
    if (!lane) r[row] = 1.0f / sum;
}

// part[b,ic,j] = sum_{i in chunk} r[b,i] * xh[b,i,j]
// grid (RCH, BATCH), block 128: each thread owns 8 consecutive columns (16B loads)
__global__ void colsum_h_kernel(const __half* __restrict__ xh,
                                const float* __restrict__ r,
                                float* __restrict__ part) {
    int ic = blockIdx.x, b = blockIdx.y;
    int j0 = threadIdx.x * 8;
    const __half* base = xh + ((size_t)(b * N + ic * RPC)) * N + j0;
    const float*  rp   = r + b * N + ic * RPC;
    float s[8] = {0, 0, 0, 0, 0, 0, 0, 0};
#pragma unroll 4
    for (int i = 0; i < RPC; ++i) {
        float rv = rp[i];
        float4 raw = *(const float4*)(base + (size_t)i * N);
        const __half* hp = (const __half*)&raw;
#pragma unroll
        for (int k = 0; k < 8; ++k) s[k] += rv * __half2float(hp[k]);
    }
    float* pp = part + ((size_t)(b * RCH + ic)) * N + j0;
    *(float4*)(pp)     = make_float4(s[0], s[1], s[2], s[3]);
    *(float4*)(pp + 4) = make_float4(s[4], s[5], s[6], s[7]);
}

// c[b,j] = 1 / sum_ic part[b,ic,j]
__global__ void colreduce_kernel(const float* __restrict__ part,
                                 float* __restrict__ c) {
    int idx = blockIdx.x * 256 + threadIdx.x;   // b*N + j
    int b = idx >> 10, j = idx & (N - 1);
    const float* pp = part + (size_t)b * RCH * N + j;
    float s = 0.0f;
#pragma unroll
    for (int ic = 0; ic < RCH; ++ic) s += pp[(size_t)ic * N];
    c[idx] = 1.0f / s;
}

// out = r[b,i] * (x+eps) * c[b,j]  — full fp32 precision on the output pass
__global__ void final_kernel(const float* __restrict__ x,
                             const float* __restrict__ r,
                             const float* __restrict__ c,
                             float* __restrict__ out) {
    size_t idx = ((size_t)blockIdx.x * blockDim.x + threadIdx.x) * 4;
    int row = (int)(idx >> 10);          // b*N + i
    int b   = row >> 10;
    int j   = (int)(idx & (N - 1));
    float4 xv = *(const float4*)(x + idx);
    float4 cv = *(const float4*)(c + b * N + j);
    float  rv = r[row];
    float4 o;
    o.x = rv * (xv.x + EPS) * cv.x;
    o.y = rv * (xv.y + EPS) * cv.y;
    o.z = rv * (xv.z + EPS) * cv.z;
    o.w = rv * (xv.w + EPS) * cv.w;
    *(float4*)(out + idx) = o;
}

extern "C" void kernel_launch(void* const* d_in, const int* in_sizes, int n_in,
                              void* d_out, int out_size, void* d_ws, size_t ws_size,
                              hipStream_t stream) {
    const float* x = (const float*)d_in[0];
    float* out = (float*)d_out;

    __half* xh  = (__half*)d_ws;
    float*  r   = (float*)((char*)d_ws + (size_t)BATCH * N * N * 2);
    float*  c   = r + BATCH * N;
    float*  part = c + BATCH * N;

    // iteration 1 rowsum fused with fp16 conversion (c0 = 1)
    convert_rowsum_kernel<<<(BATCH * N) / 4, 256, 0, stream>>>(x, xh, r);
    for (int t = 0; t < ITERS; ++t) {
        colsum_h_kernel<<<dim3(RCH, BATCH), 128, 0, stream>>>(xh, r, part);
        colreduce_kernel<<<(BATCH * N) / 256, 256, 0, stream>>>(part, c);
        if (t < ITERS - 1)
            rowsum_h_kernel<<<(BATCH * N) / 4, 256, 0, stream>>>(xh, c, r);
    }
    final_kernel<<<(BATCH * N * N / 4) / 256, 256, 0, stream>>>(x, r, c, out);
}

// Round 4
// 254.275 us; speedup vs baseline: 1.8344x; 1.2291x over previous
//
#include <hip/hip_runtime.h>

#define BATCH 32
#define N 1024
#define EPS 0.001f
#define ITERS 10
#define RCH 32            // row chunks for colsum partials
#define RPC (N / RCH)     // 32 rows per chunk

typedef float v2f __attribute__((vector_size(8)));

// ws layout (bytes):
//   xq   [BATCH*N*N] fp8 e4m3 = 33,554,432 B
//   r    [BATCH*N]   fp32     =    131,072 B
//   c    [BATCH*N]   fp32     =    131,072 B
//   part [BATCH*RCH*N] fp32   =  4,194,304 B

// Fused: xq = fp8(x+eps); r = 1/rowsum(x+eps)  (iteration-1 rowsum, c0 = 1,
// computed from exact fp32 values — free).  One wave per row, 4 waves/block.
__global__ void convert_rowsum_kernel(const float* __restrict__ x,
                                      unsigned char* __restrict__ xq,
                                      float* __restrict__ r) {
    int wave = threadIdx.x >> 6, lane = threadIdx.x & 63;
    int row  = blockIdx.x * 4 + wave;          // [0, BATCH*N)
    const float* xrow = x + (size_t)row * N;
    unsigned char* qrow = xq + (size_t)row * N;
    float sum = 0.0f;
#pragma unroll
    for (int k = 0; k < 4; ++k) {
        int j = k * 256 + lane * 4;
        float4 xv = *(const float4*)(xrow + j);
        float a = xv.x + EPS, b = xv.y + EPS, cc = xv.z + EPS, d = xv.w + EPS;
        sum += a + b + cc + d;
        int w = __builtin_amdgcn_cvt_pk_fp8_f32(a, b, 0, false);   // bytes 0-1
        w     = __builtin_amdgcn_cvt_pk_fp8_f32(cc, d, w, true);   // bytes 2-3
        *(int*)(qrow + j) = w;
    }
#pragma unroll
    for (int off = 32; off; off >>= 1) sum += __shfl_xor(sum, off);
    if (!lane) r[row] = 1.0f / sum;
}

// r[row] = 1 / sum_j xq[row,j] * c[b,j]   (fp8 x, fp32 accumulate)
// one wave per row; lane owns 16 consecutive fp8 (one int4 load)
__global__ void rowsum_q_kernel(const unsigned char* __restrict__ xq,
                                const float* __restrict__ c,
                                float* __restrict__ r) {
    int wave = threadIdx.x >> 6, lane = threadIdx.x & 63;
    int row  = blockIdx.x * 4 + wave;
    int b    = row >> 10;
    int j0   = lane * 16;
    int4 raw = *(const int4*)(xq + (size_t)row * N + j0);
    const float* cb = c + b * N + j0;
    float4 c0 = *(const float4*)(cb);
    float4 c1 = *(const float4*)(cb + 4);
    float4 c2 = *(const float4*)(cb + 8);
    float4 c3 = *(const float4*)(cb + 12);
    float sum;
    {
        v2f f01 = __builtin_amdgcn_cvt_pk_f32_fp8(raw.x, false);
        v2f f23 = __builtin_amdgcn_cvt_pk_f32_fp8(raw.x, true);
        sum = c0.x * f01[0] + c0.y * f01[1] + c0.z * f23[0] + c0.w * f23[1];
    }
    {
        v2f f01 = __builtin_amdgcn_cvt_pk_f32_fp8(raw.y, false);
        v2f f23 = __builtin_amdgcn_cvt_pk_f32_fp8(raw.y, true);
        sum += c1.x * f01[0] + c1.y * f01[1] + c1.z * f23[0] + c1.w * f23[1];
    }
    {
        v2f f01 = __builtin_amdgcn_cvt_pk_f32_fp8(raw.z, false);
        v2f f23 = __builtin_amdgcn_cvt_pk_f32_fp8(raw.z, true);
        sum += c2.x * f01[0] + c2.y * f01[1] + c2.z * f23[0] + c2.w * f23[1];
    }
    {
        v2f f01 = __builtin_amdgcn_cvt_pk_f32_fp8(raw.w, false);
        v2f f23 = __builtin_amdgcn_cvt_pk_f32_fp8(raw.w, true);
        sum += c3.x * f01[0] + c3.y * f01[1] + c3.z * f23[0] + c3.w * f23[1];
    }
#pragma unroll
    for (int off = 32; off; off >>= 1) sum += __shfl_xor(sum, off);
    if (!lane) r[row] = 1.0f / sum;
}

// part[b,ic,j] = sum_{i in chunk} r[b,i] * xq[b,i,j]
// grid (RCH, BATCH), block 128: thread owns 8 consecutive columns (8B loads)
__global__ void colsum_q_kernel(const unsigned char* __restrict__ xq,
                                const float* __restrict__ r,
                                float* __restrict__ part) {
    int ic = blockIdx.x, b = blockIdx.y;
    int j0 = threadIdx.x * 8;
    const unsigned char* base = xq + ((size_t)(b * N + ic * RPC)) * N + j0;
    const float* rp = r + b * N + ic * RPC;
    float s[8] = {0, 0, 0, 0, 0, 0, 0, 0};
#pragma unroll 8
    for (int i = 0; i < RPC; ++i) {
        float rv = rp[i];
        int2 w = *(const int2*)(base + (size_t)i * N);
        v2f f01 = __builtin_amdgcn_cvt_pk_f32_fp8(w.x, false);
        v2f f23 = __builtin_amdgcn_cvt_pk_f32_fp8(w.x, true);
        v2f f45 = __builtin_amdgcn_cvt_pk_f32_fp8(w.y, false);
        v2f f67 = __builtin_amdgcn_cvt_pk_f32_fp8(w.y, true);
        s[0] += rv * f01[0];  s[1] += rv * f01[1];
        s[2] += rv * f23[0];  s[3] += rv * f23[1];
        s[4] += rv * f45[0];  s[5] += rv * f45[1];
        s[6] += rv * f67[0];  s[7] += rv * f67[1];
    }
    float* pp = part + ((size_t)(b * RCH + ic)) * N + j0;
    *(float4*)(pp)     = make_float4(s[0], s[1], s[2], s[3]);
    *(float4*)(pp + 4) = make_float4(s[4], s[5], s[6], s[7]);
}

// c[b,j] = 1 / sum_ic part[b,ic,j]
__global__ void colreduce_kernel(const float* __restrict__ part,
                                 float* __restrict__ c) {
    int idx = blockIdx.x * 256 + threadIdx.x;   // b*N + j
    int b = idx >> 10, j = idx & (N - 1);
    const float* pp = part + (size_t)b * RCH * N + j;
    float s = 0.0f;
#pragma unroll
    for (int ic = 0; ic < RCH; ++ic) s += pp[(size_t)ic * N];
    c[idx] = 1.0f / s;
}

// out = r[b,i] * (x+eps) * c[b,j]  — full fp32 precision on the output pass
__global__ void final_kernel(const float* __restrict__ x,
                             const float* __restrict__ r,
                             const float* __restrict__ c,
                             float* __restrict__ out) {
    size_t idx = ((size_t)blockIdx.x * blockDim.x + threadIdx.x) * 4;
    int row = (int)(idx >> 10);          // b*N + i
    int b   = row >> 10;
    int j   = (int)(idx & (N - 1));
    float4 xv = *(const float4*)(x + idx);
    float4 cv = *(const float4*)(c + b * N + j);
    float  rv = r[row];
    float4 o;
    o.x = rv * (xv.x + EPS) * cv.x;
    o.y = rv * (xv.y + EPS) * cv.y;
    o.z = rv * (xv.z + EPS) * cv.z;
    o.w = rv * (xv.w + EPS) * cv.w;
    *(float4*)(out + idx) = o;
}

extern "C" void kernel_launch(void* const* d_in, const int* in_sizes, int n_in,
                              void* d_out, int out_size, void* d_ws, size_t ws_size,
                              hipStream_t stream) {
    const float* x = (const float*)d_in[0];
    float* out = (float*)d_out;

    unsigned char* xq = (unsigned char*)d_ws;
    float* r    = (float*)((char*)d_ws + (size_t)BATCH * N * N);
    float* c    = r + BATCH * N;
    float* part = c + BATCH * N;

    // iteration 1 rowsum fused with fp8 conversion (c0 = 1)
    convert_rowsum_kernel<<<(BATCH * N) / 4, 256, 0, stream>>>(x, xq, r);
    for (int t = 0; t < ITERS; ++t) {
        colsum_q_kernel<<<dim3(RCH, BATCH), 128, 0, stream>>>(xq, r, part);
        colreduce_kernel<<<(BATCH * N) / 256, 256, 0, stream>>>(part, c);
        if (t < ITERS - 1)
            rowsum_q_kernel<<<(BATCH * N) / 4, 256, 0, stream>>>(xq, c, r);
    }
    final_kernel<<<(BATCH * N * N / 4) / 256, 256, 0, stream>>>(x, r, c, out);
}

// Round 5
// 218.564 us; speedup vs baseline: 2.1342x; 1.1634x over previous
//
#include <hip/hip_runtime.h>

#define BATCH 32
#define N 1024
#define EPS 0.001f
#define ITERS 10
#define TR 64              // rows per fused-kernel block tile
#define NCH (N / TR)       // 16 row-chunks per batch

typedef float v2f __attribute__((vector_size(8)));

// ws layout (bytes):
//   xq   [BATCH*N*N] fp8 e4m3 = 33,554,432 B
//   r    [BATCH*N]   fp32     =    131,072 B
//   c    [BATCH*N]   fp32     =    131,072 B
//   part [BATCH*NCH*N] fp32   =  2,097,152 B

// xq = fp8(x + eps)
__global__ void convert_kernel(const float* __restrict__ x,
                               unsigned char* __restrict__ xq) {
    size_t i4 = ((size_t)blockIdx.x * 256 + threadIdx.x) * 4;
    float4 xv = *(const float4*)(x + i4);
    int w = __builtin_amdgcn_cvt_pk_fp8_f32(xv.x + EPS, xv.y + EPS, 0, false);
    w     = __builtin_amdgcn_cvt_pk_fp8_f32(xv.z + EPS, xv.w + EPS, w, true);
    *(int*)(xq + i4) = w;
}

__device__ inline float dot16_fp8(const int4 raw, const float* creg) {
    float s = 0.0f;
    v2f f;
    f = __builtin_amdgcn_cvt_pk_f32_fp8(raw.x, false); s += creg[0]*f[0]  + creg[1]*f[1];
    f = __builtin_amdgcn_cvt_pk_f32_fp8(raw.x, true);  s += creg[2]*f[0]  + creg[3]*f[1];
    f = __builtin_amdgcn_cvt_pk_f32_fp8(raw.y, false); s += creg[4]*f[0]  + creg[5]*f[1];
    f = __builtin_amdgcn_cvt_pk_f32_fp8(raw.y, true);  s += creg[6]*f[0]  + creg[7]*f[1];
    f = __builtin_amdgcn_cvt_pk_f32_fp8(raw.z, false); s += creg[8]*f[0]  + creg[9]*f[1];
    f = __builtin_amdgcn_cvt_pk_f32_fp8(raw.z, true);  s += creg[10]*f[0] + creg[11]*f[1];
    f = __builtin_amdgcn_cvt_pk_f32_fp8(raw.w, false); s += creg[12]*f[0] + creg[13]*f[1];
    f = __builtin_amdgcn_cvt_pk_f32_fp8(raw.w, true);  s += creg[14]*f[0] + creg[15]*f[1];
    return s;
}

// One Sinkhorn iteration, single pass over xq.
// Block = 64 complete rows of one batch. Phase 1: stage rows in LDS, compute
// r = 1/(M·c) per row (c from prev iter; FIRST -> c=1). Phase 2: column
// partials part[b,chunk,j] = sum_i r_i * M[i,j] from LDS.
template<bool FIRST>
__global__ __launch_bounds__(256, 2)
void sink_iter_kernel(const unsigned char* __restrict__ xq,
                      const float* __restrict__ c,
                      float* __restrict__ part,
                      float* __restrict__ r_out) {
    __shared__ unsigned char tile[TR * N];
    __shared__ float r_sh[TR];
    const int chunk = blockIdx.x, b = blockIdx.y;
    const int wave = threadIdx.x >> 6, lane = threadIdx.x & 63;
    const int j0 = lane * 16;

    // this lane's 16 columns of c, in registers
    float creg[16];
    if (FIRST) {
#pragma unroll
        for (int k = 0; k < 16; ++k) creg[k] = 1.0f;
    } else {
        const float* cb = c + b * N + j0;
        float4 c0 = *(const float4*)(cb);
        float4 c1 = *(const float4*)(cb + 4);
        float4 c2 = *(const float4*)(cb + 8);
        float4 c3 = *(const float4*)(cb + 12);
        creg[0]=c0.x; creg[1]=c0.y; creg[2]=c0.z; creg[3]=c0.w;
        creg[4]=c1.x; creg[5]=c1.y; creg[6]=c1.z; creg[7]=c1.w;
        creg[8]=c2.x; creg[9]=c2.y; creg[10]=c2.z; creg[11]=c2.w;
        creg[12]=c3.x; creg[13]=c3.y; creg[14]=c3.z; creg[15]=c3.w;
    }

    const size_t row0 = (size_t)b * N + chunk * TR;

    // Phase 1: 16 rows per wave; stage + rowsum
#pragma unroll 4
    for (int il = 0; il < TR / 4; ++il) {
        int rl = wave * (TR / 4) + il;
        int4 raw = *(const int4*)(xq + (row0 + rl) * N + j0);
        *(int4*)(&tile[rl * N + j0]) = raw;
        float sum = dot16_fp8(raw, creg);
#pragma unroll
        for (int off = 32; off; off >>= 1) sum += __shfl_xor(sum, off);
        float rv = 1.0f / sum;
        if (!lane) r_sh[rl] = rv;
        if (!lane) r_out[row0 + rl] = rv;
    }
    __syncthreads();

    // Phase 2: thread owns 4 columns; accumulate over the 64 staged rows
    const int jc = threadIdx.x * 4;
    float s0 = 0, s1 = 0, s2 = 0, s3 = 0;
#pragma unroll 8
    for (int i = 0; i < TR; ++i) {
        float rv = r_sh[i];
        int w = *(const int*)(&tile[i * N + jc]);
        v2f f01 = __builtin_amdgcn_cvt_pk_f32_fp8(w, false);
        v2f f23 = __builtin_amdgcn_cvt_pk_f32_fp8(w, true);
        s0 += rv * f01[0];  s1 += rv * f01[1];
        s2 += rv * f23[0];  s3 += rv * f23[1];
    }
    *(float4*)(part + ((size_t)(b * NCH + chunk)) * N + jc) =
        make_float4(s0, s1, s2, s3);
}

// c[b,j] = 1 / sum_ch part[b,ch,j]
__global__ void colreduce_kernel(const float* __restrict__ part,
                                 float* __restrict__ c) {
    int idx = blockIdx.x * 256 + threadIdx.x;   // b*N + j
    int b = idx >> 10, j = idx & (N - 1);
    const float* pp = part + (size_t)b * NCH * N + j;
    float s = 0.0f;
#pragma unroll
    for (int ch = 0; ch < NCH; ++ch) s += pp[(size_t)ch * N];
    c[idx] = 1.0f / s;
}

// out = r[b,i] * (x+eps) * c[b,j]  — full fp32 precision on the output pass
__global__ void final_kernel(const float* __restrict__ x,
                             const float* __restrict__ r,
                             const float* __restrict__ c,
                             float* __restrict__ out) {
    size_t idx = ((size_t)blockIdx.x * blockDim.x + threadIdx.x) * 4;
    int row = (int)(idx >> 10);          // b*N + i
    int b   = row >> 10;
    int j   = (int)(idx & (N - 1));
    float4 xv = *(const float4*)(x + idx);
    float4 cv = *(const float4*)(c + b * N + j);
    float  rv = r[row];
    float4 o;
    o.x = rv * (xv.x + EPS) * cv.x;
    o.y = rv * (xv.y + EPS) * cv.y;
    o.z = rv * (xv.z + EPS) * cv.z;
    o.w = rv * (xv.w + EPS) * cv.w;
    *(float4*)(out + idx) = o;
}

extern "C" void kernel_launch(void* const* d_in, const int* in_sizes, int n_in,
                              void* d_out, int out_size, void* d_ws, size_t ws_size,
                              hipStream_t stream) {
    const float* x = (const float*)d_in[0];
    float* out = (float*)d_out;

    unsigned char* xq = (unsigned char*)d_ws;
    float* r    = (float*)((char*)d_ws + (size_t)BATCH * N * N);
    float* c    = r + BATCH * N;
    float* part = c + BATCH * N;

    convert_kernel<<<(BATCH * N * N / 4) / 256, 256, 0, stream>>>(x, xq);

    sink_iter_kernel<true><<<dim3(NCH, BATCH), 256, 0, stream>>>(xq, nullptr, part, r);
    colreduce_kernel<<<(BATCH * N) / 256, 256, 0, stream>>>(part, c);
    for (int t = 1; t < ITERS; ++t) {
        sink_iter_kernel<false><<<dim3(NCH, BATCH), 256, 0, stream>>>(xq, c, part, r);
        colreduce_kernel<<<(BATCH * N) / 256, 256, 0, stream>>>(part, c);
    }
    final_kernel<<<(BATCH * N * N / 4) / 256, 256, 0, stream>>>(x, r, c, out);
}